// Round 6
// baseline (714.276 us; speedup 1.0000x reference)
//
#include <hip/hip_runtime.h>

#define D 64
#define NEG_SLOPE 0.01f
#define CB_SHIFT 10          // 1024 nodes per coarse bucket
#define CB_NODES 1024
#define MAXCB 128            // supports N <= 131072
#define CHUNK 8192           // edges per scatter block
#define SADJ_CAP 18432       // LDS adj stage (72 KB)
#define SM_STRIDE 68         // 64 k + 4 pad (node-major mean/hin tile)

// ---------------------------------------------------------------------------
// Edge dtype detection: reference says int64, harness may hand int32.
// ---------------------------------------------------------------------------
__global__ void detect_kernel(const void* __restrict__ ei, int* __restrict__ flag) {
    int lane = threadIdx.x & 63;
    const int* p = (const int*)ei;
    int v = p[2 * lane + 1];
    unsigned long long b = __ballot(v != 0);
    if (lane == 0) *flag = (b == 0ULL) ? 1 : 0;
}

__device__ __forceinline__ int edge_at(const void* __restrict__ ei, long long idx, int is64) {
    if (is64) return (int)((const long long*)ei)[idx];
    return ((const int*)ei)[idx];
}

// ---------------------------------------------------------------------------
// Coarse histogram: per-block LDS hist of dst>>10, <=128 global atomics/block.
// ---------------------------------------------------------------------------
__global__ __launch_bounds__(256) void chist_kernel(
        const void* __restrict__ ei, long long E, const int* __restrict__ flagp,
        int* __restrict__ ccount, int ncb) {
    __shared__ int hist[MAXCB];
    int t = threadIdx.x;
    if (t < MAXCB) hist[t] = 0;
    __syncthreads();
    int is64 = *flagp;
    long long tid = (long long)blockIdx.x * blockDim.x + t;
    long long nt = (long long)gridDim.x * blockDim.x;
    for (long long e = tid; e < E; e += nt) {
        int d = edge_at(ei, E + e, is64);
        atomicAdd(&hist[d >> CB_SHIFT], 1);
    }
    __syncthreads();
    if (t < ncb && hist[t]) atomicAdd(&ccount[t], hist[t]);
}

// serial scan of <=128 bucket counts; also init cursors and rowptr[N]
__global__ void cscan_kernel(const int* __restrict__ ccount, int* __restrict__ cbase,
                             int* __restrict__ ccur, int* __restrict__ rowptr,
                             int ncb, int N, int E) {
    int run = 0;
    for (int b = 0; b < ncb; ++b) {
        cbase[b] = run;
        ccur[b] = run;
        run += ccount[b];
    }
    cbase[ncb] = run;
    rowptr[N] = E;
}

// ---------------------------------------------------------------------------
// Coarse scatter: LDS-sort an 8192-edge chunk into coarse-bucket order,
// reserve one contiguous global run per (block,bucket), flush packed
// (src<<10 | dstLocal) words in coalesced runs.
// ---------------------------------------------------------------------------
__global__ __launch_bounds__(256) void scatter_kernel(
        const void* __restrict__ ei, long long E, const int* __restrict__ flagp,
        int* __restrict__ ccur, unsigned* __restrict__ ebuf, int ncb) {
    __shared__ int hist[MAXCB];
    __shared__ int lofs[MAXCB];
    __shared__ int gbase[MAXCB];
    __shared__ int cur[MAXCB];
    __shared__ unsigned spk[CHUNK];
    __shared__ unsigned char sbk[CHUNK];
    int t = threadIdx.x;
    if (t < MAXCB) hist[t] = 0;
    __syncthreads();
    int is64 = *flagp;
    long long start = (long long)blockIdx.x * CHUNK;
    int ccnt = (int)min((long long)CHUNK, E - start);

    for (int i = t; i < ccnt; i += 256) {
        int d = edge_at(ei, E + start + i, is64);
        atomicAdd(&hist[d >> CB_SHIFT], 1);
    }
    __syncthreads();
    if (t == 0) {
        int run = 0;
        for (int b = 0; b < ncb; ++b) { lofs[b] = run; run += hist[b]; }
    }
    if (t < ncb && hist[t]) gbase[t] = atomicAdd(&ccur[t], hist[t]);
    __syncthreads();
    if (t < ncb) cur[t] = lofs[t];
    __syncthreads();

    for (int i = t; i < ccnt; i += 256) {
        int s = edge_at(ei, start + i, is64);
        int d = edge_at(ei, E + start + i, is64);
        int b = d >> CB_SHIFT;
        int slot = atomicAdd(&cur[b], 1);
        spk[slot] = ((unsigned)s << CB_SHIFT) | (unsigned)(d & (CB_NODES - 1));
        sbk[slot] = (unsigned char)b;
    }
    __syncthreads();

    for (int i = t; i < ccnt; i += 256) {
        int b = sbk[i];
        ebuf[gbase[b] + (i - lofs[b])] = spk[i];
    }
}

// ---------------------------------------------------------------------------
// Fine fill: one block per coarse bucket; per-node count + scan -> rowptr;
// LDS ticket placement; coalesced flush. Scattered writes stay in LDS.
// ---------------------------------------------------------------------------
__global__ __launch_bounds__(256) void finefill_kernel(
        const unsigned* __restrict__ ebuf, const int* __restrict__ cbase,
        int* __restrict__ rowptr, int* __restrict__ adj, int N) {
    __shared__ int cnt[CB_NODES];
    __shared__ int cur[CB_NODES];
    __shared__ int wpart[4];
    __shared__ int sAdj[SADJ_CAP];
    int t = threadIdx.x;
    int b = blockIdx.x;
    int e0 = cbase[b], e1 = cbase[b + 1];
    int len = e1 - e0;
    int nb = b << CB_SHIFT;

    for (int i = t; i < CB_NODES; i += 256) cnt[i] = 0;
    __syncthreads();
    for (int i = t; i < len; i += 256) {
        unsigned p = ebuf[e0 + i];
        atomicAdd(&cnt[p & (CB_NODES - 1)], 1);
    }
    __syncthreads();

    int c0 = cnt[4 * t], c1 = cnt[4 * t + 1], c2 = cnt[4 * t + 2], c3 = cnt[4 * t + 3];
    int s = c0 + c1 + c2 + c3;
    int lane = t & 63, wv = t >> 6;
    int inc = s;
    for (int off = 1; off < 64; off <<= 1) {
        int u = __shfl_up(inc, off, 64);
        if (lane >= off) inc += u;
    }
    if (lane == 63) wpart[wv] = inc;
    __syncthreads();
    int wof = 0;
    for (int w = 0; w < wv; ++w) wof += wpart[w];
    int ex = wof + inc - s;
    int o0 = ex, o1 = ex + c0, o2 = o1 + c1, o3 = o2 + c2;
    cur[4 * t] = o0; cur[4 * t + 1] = o1; cur[4 * t + 2] = o2; cur[4 * t + 3] = o3;
    {
        int g = nb + 4 * t;
        if (g < N)     rowptr[g]     = e0 + o0;
        if (g + 1 < N) rowptr[g + 1] = e0 + o1;
        if (g + 2 < N) rowptr[g + 2] = e0 + o2;
        if (g + 3 < N) rowptr[g + 3] = e0 + o3;
    }
    __syncthreads();

    int big = (len > SADJ_CAP);
    for (int i = t; i < len; i += 256) {
        unsigned p = ebuf[e0 + i];
        int dl = (int)(p & (CB_NODES - 1));
        int src = (int)(p >> CB_SHIFT);
        int pos = atomicAdd(&cur[dl], 1);
        if (big) adj[e0 + pos] = src;
        else     sAdj[pos] = src;
    }
    __syncthreads();
    if (!big) {
        for (int i = t; i < len; i += 256) adj[e0 + i] = sAdj[i];
    }
}

// ---------------------------------------------------------------------------
// One GEMM pass: acc += A_tile(sM, node-major) @ W^T, W streamed from global
// (16 KB, L1-resident). Per 4k-group: 8 ds_read_b128 (A) + 4 global b128 (W)
// + 128 FMA -> VALU-bound. Thread nodes interleaved (ng + 4i) so the 4
// concurrent LDS addresses per wave land in different banks.
// ---------------------------------------------------------------------------
__device__ __forceinline__ void gemm_pass(float acc[8][4],
        const float* __restrict__ sM, const float* __restrict__ W,
        int w, int ng, int cg) {
#pragma unroll 4
    for (int k0 = 0; k0 < 64; k0 += 4) {
        float4 wq0 = *(const float4*)(W + (cg * 4 + 0) * D + k0);
        float4 wq1 = *(const float4*)(W + (cg * 4 + 1) * D + k0);
        float4 wq2 = *(const float4*)(W + (cg * 4 + 2) * D + k0);
        float4 wq3 = *(const float4*)(W + (cg * 4 + 3) * D + k0);
#pragma unroll
        for (int i = 0; i < 8; ++i) {
            int n = w * 32 + ng + 4 * i;
            const float4 a = *(const float4*)&sM[n * SM_STRIDE + k0];
            acc[i][0] += a.x * wq0.x + a.y * wq0.y + a.z * wq0.z + a.w * wq0.w;
            acc[i][1] += a.x * wq1.x + a.y * wq1.y + a.z * wq1.z + a.w * wq1.w;
            acc[i][2] += a.x * wq2.x + a.y * wq2.y + a.z * wq2.z + a.w * wq2.w;
            acc[i][3] += a.x * wq3.x + a.y * wq3.y + a.z * wq3.z + a.w * wq3.w;
        }
    }
}

// ---------------------------------------------------------------------------
// Fused layer: 128 nodes/block. Phase 1: CSR gather -> mean directly into LDS
// (node-major float4, conflict-free). Phase 2: pass A (mean@Wl^T) from LDS,
// restage hin tile into same LDS, pass B (hin@Wr^T). Epilogue: bias + leaky
// (+ fused output head on the last layer). No mean buffer round-trip.
// ---------------------------------------------------------------------------
__global__ __launch_bounds__(256, 4) void layer_kernel(
        const float* __restrict__ hin, const int* __restrict__ rowptr,
        const int* __restrict__ adj,
        const float* __restrict__ Wl, const float* __restrict__ bl,
        const float* __restrict__ Wr,
        const float* __restrict__ Wout, const float* __restrict__ bout,
        float* __restrict__ hout, float* __restrict__ out,
        int N, int final_flag) {
    __shared__ float sM[128 * SM_STRIDE];   // 34.8 KB -> 4 blocks/CU
    int t = threadIdx.x;
    int lane = t & 63;
    int w = t >> 6;
    int node_base = blockIdx.x * 128;
    int sub = lane & 15;      // float4 slot within a feature row
    int grp = lane >> 4;      // one of 4 concurrent neighbor rows

    // ---- phase 1: gather + mean into sM (wave w owns local nodes w*32..+31) ----
    for (int nn = 0; nn < 32; ++nn) {
        int ln = w * 32 + nn;
        int i = node_base + ln;
        if (i >= N) break;
        int b0 = rowptr[i], b1 = rowptr[i + 1];
        float ax = 0.f, ay = 0.f, az = 0.f, aw = 0.f;
        for (int base = b0; base < b1; base += 64) {
            int idx = base + lane;
            int sl = (idx < b1) ? adj[idx] : 0;
            int cnt = min(64, b1 - base);
            int nq = (cnt + 3) >> 2;
#pragma unroll 4
            for (int tt = 0; tt < nq; ++tt) {
                int j = (tt << 2) + grp;
                int s = __shfl(sl, j, 64);
                if (j < cnt) {
                    const float4 v = *(const float4*)(hin + (size_t)s * D + (sub << 2));
                    ax += v.x; ay += v.y; az += v.z; aw += v.w;
                }
            }
        }
        ax += __shfl_xor(ax, 16, 64); ay += __shfl_xor(ay, 16, 64);
        az += __shfl_xor(az, 16, 64); aw += __shfl_xor(aw, 16, 64);
        ax += __shfl_xor(ax, 32, 64); ay += __shfl_xor(ay, 32, 64);
        az += __shfl_xor(az, 32, 64); aw += __shfl_xor(aw, 32, 64);
        if (grp == 0) {
            float inv = 1.0f / fmaxf((float)(b1 - b0), 1.0f);
            *(float4*)&sM[ln * SM_STRIDE + (sub << 2)] =
                make_float4(ax * inv, ay * inv, az * inv, aw * inv);
        }
    }
    __syncthreads();

    // ---- phase 2: GEMM. thread tile: 8 nodes (ng + 4i) x 4 ch (cg*4..) ----
    int ng = lane >> 4;   // 0..3
    int cg = lane & 15;   // 0..15
    float acc[8][4];
#pragma unroll
    for (int i = 0; i < 8; ++i)
#pragma unroll
        for (int j = 0; j < 4; ++j) acc[i][j] = 0.f;

    gemm_pass(acc, sM, Wl, w, ng, cg);          // pass A: mean @ Wl^T
    __syncthreads();

    // restage hin tile (node-major float4, coalesced global, conflict-free LDS)
    {
        int node = t >> 1, half = t & 1;
        int gn = node_base + node;
        if (gn >= N) gn = N - 1;
#pragma unroll
        for (int q = 0; q < 8; ++q) {
            int k0 = half * 32 + q * 4;
            const float4 v = *(const float4*)(hin + (size_t)gn * D + k0);
            *(float4*)&sM[node * SM_STRIDE + k0] = v;
        }
    }
    __syncthreads();

    gemm_pass(acc, sM, Wr, w, ng, cg);          // pass B: hin @ Wr^T

    // ---- epilogue ----
    const float4 bq = *(const float4*)&bl[cg * 4];
    const float bb[4] = {bq.x, bq.y, bq.z, bq.w};
    if (!final_flag) {
#pragma unroll
        for (int i = 0; i < 8; ++i) {
            int gn = node_base + w * 32 + ng + 4 * i;
            if (gn < N) {
                float4 r;
                float y0 = acc[i][0] + bb[0]; r.x = (y0 >= 0.f) ? y0 : NEG_SLOPE * y0;
                float y1 = acc[i][1] + bb[1]; r.y = (y1 >= 0.f) ? y1 : NEG_SLOPE * y1;
                float y2 = acc[i][2] + bb[2]; r.z = (y2 >= 0.f) ? y2 : NEG_SLOPE * y2;
                float y3 = acc[i][3] + bb[3]; r.w = (y3 >= 0.f) ? y3 : NEG_SLOPE * y3;
                *(float4*)(hout + (size_t)gn * D + cg * 4) = r;
            }
        }
    } else {
        const float4 wq = *(const float4*)&Wout[cg * 4];
        const float wv[4] = {wq.x, wq.y, wq.z, wq.w};
        float bo = bout[0];
#pragma unroll
        for (int i = 0; i < 8; ++i) {
            float p = 0.f;
#pragma unroll
            for (int j = 0; j < 4; ++j) {
                float y = acc[i][j] + bb[j];
                y = (y >= 0.f) ? y : NEG_SLOPE * y;
                p += y * wv[j];
            }
            p += __shfl_xor(p, 1, 64);
            p += __shfl_xor(p, 2, 64);
            p += __shfl_xor(p, 4, 64);
            p += __shfl_xor(p, 8, 64);
            if (cg == 0) {
                int gn = node_base + w * 32 + ng + 4 * i;
                if (gn < N) out[gn] = p + bo;
            }
        }
    }
}

extern "C" void kernel_launch(void* const* d_in, const int* in_sizes, int n_in,
                              void* d_out, int out_size, void* d_ws, size_t ws_size,
                              hipStream_t stream) {
    const float* x    = (const float*)d_in[0];
    const void*  ei   = d_in[1];
    const float* Wl1  = (const float*)d_in[2];
    const float* bl1  = (const float*)d_in[3];
    const float* Wr1  = (const float*)d_in[4];
    const float* Wl2  = (const float*)d_in[5];
    const float* bl2  = (const float*)d_in[6];
    const float* Wr2  = (const float*)d_in[7];
    const float* Wl3  = (const float*)d_in[8];
    const float* bl3  = (const float*)d_in[9];
    const float* Wr3  = (const float*)d_in[10];
    const float* Wout = (const float*)d_in[11];
    const float* bout = (const float*)d_in[12];
    float* out = (float*)d_out;

    int       N = in_sizes[0] / D;
    long long E = (long long)in_sizes[1] / 2;
    int ncb = (N + CB_NODES - 1) >> CB_SHIFT;   // <= MAXCB for N <= 131072

    // workspace layout
    char* ws = (char*)d_ws;
    int* flag = (int*)ws;
    size_t off = 256;
    int* ccount = (int*)(ws + off); off += 512;
    int* cbase  = (int*)(ws + off); off += 1024;
    int* ccur   = (int*)(ws + off); off += 512;
    int* rowptr = (int*)(ws + off); off += (((size_t)(N + 1) * 4 + 255) / 256) * 256;
    int* adj    = (int*)(ws + off); off += (((size_t)E * 4 + 255) / 256) * 256;
    float* bufA = (float*)(ws + off); off += (size_t)N * D * 4;
    float* bufB = (float*)(ws + off);
    unsigned* ebuf = (unsigned*)bufB;  // consumed by finefill before bufB's first write

    detect_kernel<<<1, 64, 0, stream>>>(ei, flag);

    // ---- CSR build via two-level counting sort (once; graph layer-invariant) ----
    hipMemsetAsync(ccount, 0, 512, stream);
    chist_kernel<<<256, 256, 0, stream>>>(ei, E, flag, ccount, ncb);
    cscan_kernel<<<1, 1, 0, stream>>>(ccount, cbase, ccur, rowptr, ncb, N, (int)E);
    int sgrid = (int)((E + CHUNK - 1) / CHUNK);
    scatter_kernel<<<sgrid, 256, 0, stream>>>(ei, E, flag, ccur, ebuf, ncb);
    finefill_kernel<<<ncb, 256, 0, stream>>>(ebuf, cbase, rowptr, adj, N);

    int lgrid = (N + 127) / 128;

    // ---- 3 fused layers (gather + GEMM + activation[, + head]) ----
    layer_kernel<<<lgrid, 256, 0, stream>>>(x,    rowptr, adj, Wl1, bl1, Wr1,
                                            Wout, bout, bufA, out, N, 0);
    layer_kernel<<<lgrid, 256, 0, stream>>>(bufA, rowptr, adj, Wl2, bl2, Wr2,
                                            Wout, bout, bufB, out, N, 0);
    layer_kernel<<<lgrid, 256, 0, stream>>>(bufB, rowptr, adj, Wl3, bl3, Wr3,
                                            Wout, bout, (float*)ws, out, N, 1);
}

// Round 7
// 665.458 us; speedup vs baseline: 1.0734x; 1.0734x over previous
//
#include <hip/hip_runtime.h>

#define D 64
#define NEG_SLOPE 0.01f
#define CB_SHIFT 10          // 1024 nodes per coarse bucket
#define CB_NODES 1024
#define MAXCB 128            // supports N <= 131072
#define CHUNK 8192           // edges per scatter block
#define SADJ_CAP 18432       // LDS adj stage (72 KB)
#define SM_STRIDE 68         // 64 k + 4 pad (node-major tile), 16B-aligned rows

// ---------------------------------------------------------------------------
// Edge dtype detection, inline per wave: if all odd int32 words of the first
// 128 are zero, the buffer is int64 (little-endian high words).
// ---------------------------------------------------------------------------
__device__ __forceinline__ int detect64(const void* __restrict__ ei) {
    int lane = threadIdx.x & 63;
    int v = ((const int*)ei)[2 * lane + 1];
    return (__ballot(v != 0) == 0ULL) ? 1 : 0;
}

__device__ __forceinline__ int edge_at(const void* __restrict__ ei, long long idx, int is64) {
    if (is64) return (int)((const long long*)ei)[idx];
    return ((const int*)ei)[idx];
}

// ---------------------------------------------------------------------------
// Coarse histogram: per-block LDS hist of dst>>10, <=128 global atomics/block.
// ---------------------------------------------------------------------------
__global__ __launch_bounds__(256) void chist_kernel(
        const void* __restrict__ ei, long long E,
        int* __restrict__ ccount, int ncb) {
    __shared__ int hist[MAXCB];
    int t = threadIdx.x;
    if (t < MAXCB) hist[t] = 0;
    int is64 = detect64(ei);
    __syncthreads();
    long long tid = (long long)blockIdx.x * blockDim.x + t;
    long long nt = (long long)gridDim.x * blockDim.x;
    for (long long e = tid; e < E; e += nt) {
        int d = edge_at(ei, E + e, is64);
        atomicAdd(&hist[d >> CB_SHIFT], 1);
    }
    __syncthreads();
    if (t < ncb && hist[t]) atomicAdd(&ccount[t], hist[t]);
}

// parallel exclusive scan of <=128 bucket counts (one block, 128 threads)
__global__ void cscan_kernel(const int* __restrict__ ccount, int* __restrict__ cbase,
                             int* __restrict__ ccur, int* __restrict__ rowptr,
                             int ncb, int N, int E) {
    __shared__ int wsum[2];
    int t = threadIdx.x;           // 128 threads
    int v = (t < ncb) ? ccount[t] : 0;
    int lane = t & 63, w = t >> 6;
    int inc = v;
    for (int off = 1; off < 64; off <<= 1) {
        int u = __shfl_up(inc, off, 64);
        if (lane >= off) inc += u;
    }
    if (lane == 63) wsum[w] = inc;
    __syncthreads();
    int ex = inc - v + ((w == 1) ? wsum[0] : 0);
    if (t < ncb) { cbase[t] = ex; ccur[t] = ex; }
    if (t == 0) { cbase[ncb] = wsum[0] + wsum[1]; rowptr[N] = E; }
}

// ---------------------------------------------------------------------------
// Coarse scatter: LDS-sort an 8192-edge chunk into coarse-bucket order,
// reserve one contiguous global run per (block,bucket), flush packed
// (src<<10 | dstLocal) words in coalesced runs.
// ---------------------------------------------------------------------------
__global__ __launch_bounds__(256) void scatter_kernel(
        const void* __restrict__ ei, long long E,
        int* __restrict__ ccur, unsigned* __restrict__ ebuf, int ncb) {
    __shared__ int hist[MAXCB];
    __shared__ int lofs[MAXCB];
    __shared__ int gbase[MAXCB];
    __shared__ int cur[MAXCB];
    __shared__ unsigned spk[CHUNK];
    __shared__ unsigned char sbk[CHUNK];
    int t = threadIdx.x;
    if (t < MAXCB) hist[t] = 0;
    int is64 = detect64(ei);
    __syncthreads();
    long long start = (long long)blockIdx.x * CHUNK;
    int ccnt = (int)min((long long)CHUNK, E - start);

    for (int i = t; i < ccnt; i += 256) {
        int d = edge_at(ei, E + start + i, is64);
        atomicAdd(&hist[d >> CB_SHIFT], 1);
    }
    __syncthreads();
    if (t == 0) {
        int run = 0;
        for (int b = 0; b < ncb; ++b) { lofs[b] = run; run += hist[b]; }
    }
    if (t < ncb && hist[t]) gbase[t] = atomicAdd(&ccur[t], hist[t]);
    __syncthreads();
    if (t < ncb) cur[t] = lofs[t];
    __syncthreads();

    for (int i = t; i < ccnt; i += 256) {
        int s = edge_at(ei, start + i, is64);
        int d = edge_at(ei, E + start + i, is64);
        int b = d >> CB_SHIFT;
        int slot = atomicAdd(&cur[b], 1);
        spk[slot] = ((unsigned)s << CB_SHIFT) | (unsigned)(d & (CB_NODES - 1));
        sbk[slot] = (unsigned char)b;
    }
    __syncthreads();

    for (int i = t; i < ccnt; i += 256) {
        int b = sbk[i];
        ebuf[gbase[b] + (i - lofs[b])] = spk[i];
    }
}

// ---------------------------------------------------------------------------
// Fine fill: one block per coarse bucket; per-node count + scan -> rowptr;
// LDS ticket placement; coalesced flush. Scattered writes stay in LDS.
// ---------------------------------------------------------------------------
__global__ __launch_bounds__(256) void finefill_kernel(
        const unsigned* __restrict__ ebuf, const int* __restrict__ cbase,
        int* __restrict__ rowptr, int* __restrict__ adj, int N) {
    __shared__ int cnt[CB_NODES];
    __shared__ int cur[CB_NODES];
    __shared__ int wpart[4];
    __shared__ int sAdj[SADJ_CAP];
    int t = threadIdx.x;
    int b = blockIdx.x;
    int e0 = cbase[b], e1 = cbase[b + 1];
    int len = e1 - e0;
    int nb = b << CB_SHIFT;

    for (int i = t; i < CB_NODES; i += 256) cnt[i] = 0;
    __syncthreads();
    for (int i = t; i < len; i += 256) {
        unsigned p = ebuf[e0 + i];
        atomicAdd(&cnt[p & (CB_NODES - 1)], 1);
    }
    __syncthreads();

    int c0 = cnt[4 * t], c1 = cnt[4 * t + 1], c2 = cnt[4 * t + 2], c3 = cnt[4 * t + 3];
    int s = c0 + c1 + c2 + c3;
    int lane = t & 63, wv = t >> 6;
    int inc = s;
    for (int off = 1; off < 64; off <<= 1) {
        int u = __shfl_up(inc, off, 64);
        if (lane >= off) inc += u;
    }
    if (lane == 63) wpart[wv] = inc;
    __syncthreads();
    int wof = 0;
    for (int w = 0; w < wv; ++w) wof += wpart[w];
    int ex = wof + inc - s;
    int o0 = ex, o1 = ex + c0, o2 = o1 + c1, o3 = o2 + c2;
    cur[4 * t] = o0; cur[4 * t + 1] = o1; cur[4 * t + 2] = o2; cur[4 * t + 3] = o3;
    {
        int g = nb + 4 * t;
        if (g < N)     rowptr[g]     = e0 + o0;
        if (g + 1 < N) rowptr[g + 1] = e0 + o1;
        if (g + 2 < N) rowptr[g + 2] = e0 + o2;
        if (g + 3 < N) rowptr[g + 3] = e0 + o3;
    }
    __syncthreads();

    int big = (len > SADJ_CAP);
    for (int i = t; i < len; i += 256) {
        unsigned p = ebuf[e0 + i];
        int dl = (int)(p & (CB_NODES - 1));
        int src = (int)(p >> CB_SHIFT);
        int pos = atomicAdd(&cur[dl], 1);
        if (big) adj[e0 + pos] = src;
        else     sAdj[pos] = src;
    }
    __syncthreads();
    if (!big) {
        for (int i = t; i < len; i += 256) adj[e0 + i] = sAdj[i];
    }
}

// ---------------------------------------------------------------------------
// Gather+mean: wave per node (grid-stride). 16 lanes per neighbor row
// (float4/lane); unroll 4 -> 16 rows in flight. No LDS, VGPR 16 -> max
// occupancy. UNCHANGED from R5 (measured 61 us, ~3.4 TB/s LLC traffic).
// ---------------------------------------------------------------------------
__global__ __launch_bounds__(256) void agg_kernel(
        const float* __restrict__ hin, const int* __restrict__ rowptr,
        const int* __restrict__ adj, float* __restrict__ mout, int N) {
    int lane = threadIdx.x & 63;
    int sub = lane & 15;      // float4 slot within row
    int grp = lane >> 4;      // which of 4 concurrent rows
    int wid = blockIdx.x * (blockDim.x >> 6) + (threadIdx.x >> 6);
    int nw = gridDim.x * (blockDim.x >> 6);

    for (int i = wid; i < N; i += nw) {
        int b0 = rowptr[i], b1 = rowptr[i + 1];
        float ax = 0.f, ay = 0.f, az = 0.f, aw = 0.f;
        for (int base = b0; base < b1; base += 64) {
            int idx = base + lane;
            int sl = (idx < b1) ? adj[idx] : 0;   // coalesced adj chunk
            int cnt = min(64, b1 - base);
            int nq = (cnt + 3) >> 2;
#pragma unroll 4
            for (int t = 0; t < nq; ++t) {
                int j = (t << 2) + grp;
                int s = __shfl(sl, j, 64);
                if (j < cnt) {
                    const float4 v = *(const float4*)(hin + (size_t)s * D + (sub << 2));
                    ax += v.x; ay += v.y; az += v.z; aw += v.w;
                }
            }
        }
        ax += __shfl_xor(ax, 16, 64); ay += __shfl_xor(ay, 16, 64);
        az += __shfl_xor(az, 16, 64); aw += __shfl_xor(aw, 16, 64);
        ax += __shfl_xor(ax, 32, 64); ay += __shfl_xor(ay, 32, 64);
        az += __shfl_xor(az, 32, 64); aw += __shfl_xor(aw, 32, 64);
        if (grp == 0) {
            float inv = 1.0f / fmaxf((float)(b1 - b0), 1.0f);
            float4 r = make_float4(ax * inv, ay * inv, az * inv, aw * inv);
            *(float4*)(mout + (size_t)i * D + (sub << 2)) = r;
        }
    }
}

// ---------------------------------------------------------------------------
// Stage a 128-node tile node-major into LDS: thread t loads node t>>1,
// half (t&1)*32 floats as 8 float4 (coalesced-ish global, b128 LDS writes).
// ---------------------------------------------------------------------------
__device__ __forceinline__ void stage_tile(float* __restrict__ sM,
        const float* __restrict__ g, int node_base, int N, int t) {
    int node = t >> 1, half = t & 1;
    int gn = node_base + node;
    if (gn >= N) gn = N - 1;   // clamp within own block's range; masked at store
#pragma unroll
    for (int q = 0; q < 8; ++q) {
        int k0 = half * 32 + q * 4;
        const float4 v = *(const float4*)(g + (size_t)gn * D + k0);
        *(float4*)&sM[node * SM_STRIDE + k0] = v;
    }
}

// ---------------------------------------------------------------------------
// One GEMM pass: acc += A_tile(sM node-major) @ W^T, W streamed from global
// (16 KB, L1-resident). Per k0-group: 4 global b128 (W) + 8 LDS b128 (A,
// 16-lane broadcast, conflict-free) + 128 FMA/thread-group.
// ---------------------------------------------------------------------------
__device__ __forceinline__ void gemm_pass(float acc[8][4],
        const float* __restrict__ sM, const float* __restrict__ W,
        int w, int ng, int cg) {
#pragma unroll 4
    for (int k0 = 0; k0 < 64; k0 += 4) {
        float4 wq0 = *(const float4*)(W + (cg * 4 + 0) * D + k0);
        float4 wq1 = *(const float4*)(W + (cg * 4 + 1) * D + k0);
        float4 wq2 = *(const float4*)(W + (cg * 4 + 2) * D + k0);
        float4 wq3 = *(const float4*)(W + (cg * 4 + 3) * D + k0);
#pragma unroll
        for (int i = 0; i < 8; ++i) {
            int n = w * 32 + ng + 4 * i;
            const float4 a = *(const float4*)&sM[n * SM_STRIDE + k0];
            acc[i][0] += a.x * wq0.x + a.y * wq0.y + a.z * wq0.z + a.w * wq0.w;
            acc[i][1] += a.x * wq1.x + a.y * wq1.y + a.z * wq1.z + a.w * wq1.w;
            acc[i][2] += a.x * wq2.x + a.y * wq2.y + a.z * wq2.z + a.w * wq2.w;
            acc[i][3] += a.x * wq3.x + a.y * wq3.y + a.z * wq3.z + a.w * wq3.w;
        }
    }
}

// ---------------------------------------------------------------------------
// Transform v2: separate kernel, 128 nodes/block, thread tile 8x4.
// Pass A: mean(io)@Wl^T from LDS; restage hin; pass B: hin@Wr^T.
// io overwritten in place (block owns its rows). final_flag fuses the head.
// LDS 34.8 KB -> 4 blocks/CU.
// ---------------------------------------------------------------------------
__global__ __launch_bounds__(256, 4) void transform_kernel(
        float* __restrict__ io, const float* __restrict__ hin,
        const float* __restrict__ Wl, const float* __restrict__ bl,
        const float* __restrict__ Wr,
        const float* __restrict__ Wout, const float* __restrict__ bout,
        float* __restrict__ out, int N, int final_flag) {
    __shared__ float sM[128 * SM_STRIDE];
    int t = threadIdx.x;
    int lane = t & 63;
    int w = t >> 6;
    int node_base = blockIdx.x * 128;
    int ng = lane >> 4;   // 0..3
    int cg = lane & 15;   // 0..15

    float acc[8][4];
#pragma unroll
    for (int i = 0; i < 8; ++i)
#pragma unroll
        for (int j = 0; j < 4; ++j) acc[i][j] = 0.f;

    stage_tile(sM, io, node_base, N, t);        // mean tile
    __syncthreads();
    gemm_pass(acc, sM, Wl, w, ng, cg);          // pass A: mean @ Wl^T
    __syncthreads();
    stage_tile(sM, hin, node_base, N, t);       // hin tile
    __syncthreads();
    gemm_pass(acc, sM, Wr, w, ng, cg);          // pass B: hin @ Wr^T

    // epilogue
    const float4 bq = *(const float4*)&bl[cg * 4];
    const float bb[4] = {bq.x, bq.y, bq.z, bq.w};
    if (!final_flag) {
#pragma unroll
        for (int i = 0; i < 8; ++i) {
            int gn = node_base + w * 32 + ng + 4 * i;
            if (gn < N) {
                float4 r;
                float y0 = acc[i][0] + bb[0]; r.x = (y0 >= 0.f) ? y0 : NEG_SLOPE * y0;
                float y1 = acc[i][1] + bb[1]; r.y = (y1 >= 0.f) ? y1 : NEG_SLOPE * y1;
                float y2 = acc[i][2] + bb[2]; r.z = (y2 >= 0.f) ? y2 : NEG_SLOPE * y2;
                float y3 = acc[i][3] + bb[3]; r.w = (y3 >= 0.f) ? y3 : NEG_SLOPE * y3;
                *(float4*)(io + (size_t)gn * D + cg * 4) = r;
            }
        }
    } else {
        const float4 wq = *(const float4*)&Wout[cg * 4];
        const float wv[4] = {wq.x, wq.y, wq.z, wq.w};
        float bo = bout[0];
#pragma unroll
        for (int i = 0; i < 8; ++i) {
            float p = 0.f;
#pragma unroll
            for (int j = 0; j < 4; ++j) {
                float y = acc[i][j] + bb[j];
                y = (y >= 0.f) ? y : NEG_SLOPE * y;
                p += y * wv[j];
            }
            p += __shfl_xor(p, 1, 64);
            p += __shfl_xor(p, 2, 64);
            p += __shfl_xor(p, 4, 64);
            p += __shfl_xor(p, 8, 64);
            if (cg == 0) {
                int gn = node_base + w * 32 + ng + 4 * i;
                if (gn < N) out[gn] = p + bo;
            }
        }
    }
}

extern "C" void kernel_launch(void* const* d_in, const int* in_sizes, int n_in,
                              void* d_out, int out_size, void* d_ws, size_t ws_size,
                              hipStream_t stream) {
    const float* x    = (const float*)d_in[0];
    const void*  ei   = d_in[1];
    const float* Wl1  = (const float*)d_in[2];
    const float* bl1  = (const float*)d_in[3];
    const float* Wr1  = (const float*)d_in[4];
    const float* Wl2  = (const float*)d_in[5];
    const float* bl2  = (const float*)d_in[6];
    const float* Wr2  = (const float*)d_in[7];
    const float* Wl3  = (const float*)d_in[8];
    const float* bl3  = (const float*)d_in[9];
    const float* Wr3  = (const float*)d_in[10];
    const float* Wout = (const float*)d_in[11];
    const float* bout = (const float*)d_in[12];
    float* out = (float*)d_out;

    int       N = in_sizes[0] / D;
    long long E = (long long)in_sizes[1] / 2;
    int ncb = (N + CB_NODES - 1) >> CB_SHIFT;   // <= MAXCB for N <= 131072

    // workspace layout
    char* ws = (char*)d_ws;
    size_t off = 256;
    int* ccount = (int*)(ws + off); off += 512;
    int* cbase  = (int*)(ws + off); off += 1024;
    int* ccur   = (int*)(ws + off); off += 512;
    int* rowptr = (int*)(ws + off); off += (((size_t)(N + 1) * 4 + 255) / 256) * 256;
    int* adj    = (int*)(ws + off); off += (((size_t)E * 4 + 255) / 256) * 256;
    float* bufA = (float*)(ws + off); off += (size_t)N * D * 4;
    float* bufB = (float*)(ws + off);
    unsigned* ebuf = (unsigned*)bufB;  // consumed by finefill before bufB's first write

    // ---- CSR build via two-level counting sort (once; graph layer-invariant) ----
    hipMemsetAsync(ccount, 0, 512, stream);
    chist_kernel<<<256, 256, 0, stream>>>(ei, E, ccount, ncb);
    cscan_kernel<<<1, 128, 0, stream>>>(ccount, cbase, ccur, rowptr, ncb, N, (int)E);
    int sgrid = (int)((E + CHUNK - 1) / CHUNK);
    scatter_kernel<<<sgrid, 256, 0, stream>>>(ei, E, ccur, ebuf, ncb);
    finefill_kernel<<<ncb, 256, 0, stream>>>(ebuf, cbase, rowptr, adj, N);

    int tgrid = (N + 127) / 128;

    // ---- layer 1: x -> bufA ----
    agg_kernel<<<4096, 256, 0, stream>>>(x, rowptr, adj, bufA, N);
    transform_kernel<<<tgrid, 256, 0, stream>>>(bufA, x, Wl1, bl1, Wr1,
                                                Wout, bout, out, N, 0);
    // ---- layer 2: bufA -> bufB ----
    agg_kernel<<<4096, 256, 0, stream>>>(bufA, rowptr, adj, bufB, N);
    transform_kernel<<<tgrid, 256, 0, stream>>>(bufB, bufA, Wl2, bl2, Wr2,
                                                Wout, bout, out, N, 0);
    // ---- layer 3 + fused head: bufB -> out ----
    agg_kernel<<<4096, 256, 0, stream>>>(bufB, rowptr, adj, bufA, N);
    transform_kernel<<<tgrid, 256, 0, stream>>>(bufA, bufB, Wl3, bl3, Wr3,
                                                Wout, bout, out, N, 1);
}

// Round 8
// 444.126 us; speedup vs baseline: 1.6083x; 1.4984x over previous
//
#include <hip/hip_runtime.h>

#define D 64
#define NEG_SLOPE 0.01f
#define CB_SHIFT 10          // 1024 nodes per coarse bucket
#define CB_NODES 1024
#define MAXCB 128            // supports N <= 131072
#define CHUNK 8192           // edges per scatter block
#define SADJ_CAP 18432       // LDS adj stage (72 KB)
#define SA_STRIDE 132        // 128 nodes + 4 pad (k-major tile)
#define SW_STRIDE 68         // 64 ch + 4 pad

// ---------------------------------------------------------------------------
// Edge dtype detection, inline per wave: if all odd int32 words of the first
// 128 are zero, the buffer is int64 (little-endian high words).
// ---------------------------------------------------------------------------
__device__ __forceinline__ int detect64(const void* __restrict__ ei) {
    int lane = threadIdx.x & 63;
    int v = ((const int*)ei)[2 * lane + 1];
    return (__ballot(v != 0) == 0ULL) ? 1 : 0;
}

__device__ __forceinline__ int edge_at(const void* __restrict__ ei, long long idx, int is64) {
    if (is64) return (int)((const long long*)ei)[idx];
    return ((const int*)ei)[idx];
}

// ---------------------------------------------------------------------------
// Coarse histogram: per-block LDS hist of dst>>10, <=128 global atomics/block.
// ---------------------------------------------------------------------------
__global__ __launch_bounds__(256) void chist_kernel(
        const void* __restrict__ ei, long long E,
        int* __restrict__ ccount, int ncb) {
    __shared__ int hist[MAXCB];
    int t = threadIdx.x;
    if (t < MAXCB) hist[t] = 0;
    int is64 = detect64(ei);
    __syncthreads();
    long long tid = (long long)blockIdx.x * blockDim.x + t;
    long long nt = (long long)gridDim.x * blockDim.x;
    for (long long e = tid; e < E; e += nt) {
        int d = edge_at(ei, E + e, is64);
        atomicAdd(&hist[d >> CB_SHIFT], 1);
    }
    __syncthreads();
    if (t < ncb && hist[t]) atomicAdd(&ccount[t], hist[t]);
}

// parallel exclusive scan of <=128 bucket counts (one block, 128 threads)
__global__ void cscan_kernel(const int* __restrict__ ccount, int* __restrict__ cbase,
                             int* __restrict__ ccur, int* __restrict__ rowptr,
                             int ncb, int N, int E) {
    __shared__ int wsum[2];
    int t = threadIdx.x;           // 128 threads
    int v = (t < ncb) ? ccount[t] : 0;
    int lane = t & 63, w = t >> 6;
    int inc = v;
    for (int off = 1; off < 64; off <<= 1) {
        int u = __shfl_up(inc, off, 64);
        if (lane >= off) inc += u;
    }
    if (lane == 63) wsum[w] = inc;
    __syncthreads();
    int ex = inc - v + ((w == 1) ? wsum[0] : 0);
    if (t < ncb) { cbase[t] = ex; ccur[t] = ex; }
    if (t == 0) { cbase[ncb] = wsum[0] + wsum[1]; rowptr[N] = E; }
}

// ---------------------------------------------------------------------------
// Coarse scatter: LDS-sort an 8192-edge chunk into coarse-bucket order,
// reserve one contiguous global run per (block,bucket), flush packed
// (src<<10 | dstLocal) words in coalesced runs.
// ---------------------------------------------------------------------------
__global__ __launch_bounds__(256) void scatter_kernel(
        const void* __restrict__ ei, long long E,
        int* __restrict__ ccur, unsigned* __restrict__ ebuf, int ncb) {
    __shared__ int hist[MAXCB];
    __shared__ int lofs[MAXCB];
    __shared__ int gbase[MAXCB];
    __shared__ int cur[MAXCB];
    __shared__ unsigned spk[CHUNK];
    __shared__ unsigned char sbk[CHUNK];
    int t = threadIdx.x;
    if (t < MAXCB) hist[t] = 0;
    int is64 = detect64(ei);
    __syncthreads();
    long long start = (long long)blockIdx.x * CHUNK;
    int ccnt = (int)min((long long)CHUNK, E - start);

    for (int i = t; i < ccnt; i += 256) {
        int d = edge_at(ei, E + start + i, is64);
        atomicAdd(&hist[d >> CB_SHIFT], 1);
    }
    __syncthreads();
    if (t == 0) {
        int run = 0;
        for (int b = 0; b < ncb; ++b) { lofs[b] = run; run += hist[b]; }
    }
    if (t < ncb && hist[t]) gbase[t] = atomicAdd(&ccur[t], hist[t]);
    __syncthreads();
    if (t < ncb) cur[t] = lofs[t];
    __syncthreads();

    for (int i = t; i < ccnt; i += 256) {
        int s = edge_at(ei, start + i, is64);
        int d = edge_at(ei, E + start + i, is64);
        int b = d >> CB_SHIFT;
        int slot = atomicAdd(&cur[b], 1);
        spk[slot] = ((unsigned)s << CB_SHIFT) | (unsigned)(d & (CB_NODES - 1));
        sbk[slot] = (unsigned char)b;
    }
    __syncthreads();

    for (int i = t; i < ccnt; i += 256) {
        int b = sbk[i];
        ebuf[gbase[b] + (i - lofs[b])] = spk[i];
    }
}

// ---------------------------------------------------------------------------
// Fine fill: one block per coarse bucket; per-node count + scan -> rowptr;
// LDS ticket placement; coalesced flush. Scattered writes stay in LDS.
// ---------------------------------------------------------------------------
__global__ __launch_bounds__(256) void finefill_kernel(
        const unsigned* __restrict__ ebuf, const int* __restrict__ cbase,
        int* __restrict__ rowptr, int* __restrict__ adj, int N) {
    __shared__ int cnt[CB_NODES];
    __shared__ int cur[CB_NODES];
    __shared__ int wpart[4];
    __shared__ int sAdj[SADJ_CAP];
    int t = threadIdx.x;
    int b = blockIdx.x;
    int e0 = cbase[b], e1 = cbase[b + 1];
    int len = e1 - e0;
    int nb = b << CB_SHIFT;

    for (int i = t; i < CB_NODES; i += 256) cnt[i] = 0;
    __syncthreads();
    for (int i = t; i < len; i += 256) {
        unsigned p = ebuf[e0 + i];
        atomicAdd(&cnt[p & (CB_NODES - 1)], 1);
    }
    __syncthreads();

    int c0 = cnt[4 * t], c1 = cnt[4 * t + 1], c2 = cnt[4 * t + 2], c3 = cnt[4 * t + 3];
    int s = c0 + c1 + c2 + c3;
    int lane = t & 63, wv = t >> 6;
    int inc = s;
    for (int off = 1; off < 64; off <<= 1) {
        int u = __shfl_up(inc, off, 64);
        if (lane >= off) inc += u;
    }
    if (lane == 63) wpart[wv] = inc;
    __syncthreads();
    int wof = 0;
    for (int w = 0; w < wv; ++w) wof += wpart[w];
    int ex = wof + inc - s;
    int o0 = ex, o1 = ex + c0, o2 = o1 + c1, o3 = o2 + c2;
    cur[4 * t] = o0; cur[4 * t + 1] = o1; cur[4 * t + 2] = o2; cur[4 * t + 3] = o3;
    {
        int g = nb + 4 * t;
        if (g < N)     rowptr[g]     = e0 + o0;
        if (g + 1 < N) rowptr[g + 1] = e0 + o1;
        if (g + 2 < N) rowptr[g + 2] = e0 + o2;
        if (g + 3 < N) rowptr[g + 3] = e0 + o3;
    }
    __syncthreads();

    int big = (len > SADJ_CAP);
    for (int i = t; i < len; i += 256) {
        unsigned p = ebuf[e0 + i];
        int dl = (int)(p & (CB_NODES - 1));
        int src = (int)(p >> CB_SHIFT);
        int pos = atomicAdd(&cur[dl], 1);
        if (big) adj[e0 + pos] = src;
        else     sAdj[pos] = src;
    }
    __syncthreads();
    if (!big) {
        for (int i = t; i < len; i += 256) adj[e0 + i] = sAdj[i];
    }
}

// ---------------------------------------------------------------------------
// Gather+mean: wave per node (grid-stride). 16 lanes per neighbor row
// (float4/lane); unroll 4 -> 16 rows in flight. No LDS, VGPR 16 -> max
// occupancy. UNCHANGED (measured 61 us, ~3.4 TB/s LLC traffic, WRITE clean).
// ---------------------------------------------------------------------------
__global__ __launch_bounds__(256) void agg_kernel(
        const float* __restrict__ hin, const int* __restrict__ rowptr,
        const int* __restrict__ adj, float* __restrict__ mout, int N) {
    int lane = threadIdx.x & 63;
    int sub = lane & 15;      // float4 slot within row
    int grp = lane >> 4;      // which of 4 concurrent rows
    int wid = blockIdx.x * (blockDim.x >> 6) + (threadIdx.x >> 6);
    int nw = gridDim.x * (blockDim.x >> 6);

    for (int i = wid; i < N; i += nw) {
        int b0 = rowptr[i], b1 = rowptr[i + 1];
        float ax = 0.f, ay = 0.f, az = 0.f, aw = 0.f;
        for (int base = b0; base < b1; base += 64) {
            int idx = base + lane;
            int sl = (idx < b1) ? adj[idx] : 0;   // coalesced adj chunk
            int cnt = min(64, b1 - base);
            int nq = (cnt + 3) >> 2;
#pragma unroll 4
            for (int t = 0; t < nq; ++t) {
                int j = (t << 2) + grp;
                int s = __shfl(sl, j, 64);
                if (j < cnt) {
                    const float4 v = *(const float4*)(hin + (size_t)s * D + (sub << 2));
                    ax += v.x; ay += v.y; az += v.z; aw += v.w;
                }
            }
        }
        ax += __shfl_xor(ax, 16, 64); ay += __shfl_xor(ay, 16, 64);
        az += __shfl_xor(az, 16, 64); aw += __shfl_xor(aw, 16, 64);
        ax += __shfl_xor(ax, 32, 64); ay += __shfl_xor(ay, 32, 64);
        az += __shfl_xor(az, 32, 64); aw += __shfl_xor(aw, 32, 64);
        if (grp == 0) {
            float inv = 1.0f / fmaxf((float)(b1 - b0), 1.0f);
            float4 r = make_float4(ax * inv, ay * inv, az * inv, aw * inv);
            *(float4*)(mout + (size_t)i * D + (sub << 2)) = r;
        }
    }
}

// ---------------------------------------------------------------------------
// R5-proven k-major staging: 128-node x 64-k tile TRANSPOSED into LDS.
// ---------------------------------------------------------------------------
__device__ __forceinline__ void stage_tile_T(float* __restrict__ sA,
        const float* __restrict__ g, int node_base, int N, int t) {
    int nq = t >> 4;   // 0..15
    int kq = t & 15;   // 0..15
#pragma unroll
    for (int p = 0; p < 8; ++p) {
        int node = p * 16 + nq;
        int gn = node_base + node;
        if (gn >= N) gn = N - 1;   // clamp; garbage nodes masked at store
        const float4 v = *(const float4*)(g + (size_t)gn * D + (kq << 2));
        sA[(kq * 4 + 0) * SA_STRIDE + node] = v.x;
        sA[(kq * 4 + 1) * SA_STRIDE + node] = v.y;
        sA[(kq * 4 + 2) * SA_STRIDE + node] = v.z;
        sA[(kq * 4 + 3) * SA_STRIDE + node] = v.w;
    }
}

__device__ __forceinline__ void stage_w_T(float* __restrict__ sW,
        const float* __restrict__ W, int t) {
    int cq = t >> 4;
    int kq = t & 15;
#pragma unroll
    for (int p = 0; p < 4; ++p) {
        int c = p * 16 + cq;
        const float4 v = *(const float4*)(W + c * D + (kq << 2));
        sW[(kq * 4 + 0) * SW_STRIDE + c] = v.x;
        sW[(kq * 4 + 1) * SW_STRIDE + c] = v.y;
        sW[(kq * 4 + 2) * SW_STRIDE + c] = v.z;
        sW[(kq * 4 + 3) * SW_STRIDE + c] = v.w;
    }
}

__device__ __forceinline__ void kloop(float acc[8][4],
        const float* __restrict__ sA, const float* __restrict__ sW,
        int ng, int cg) {
#pragma unroll 4
    for (int k = 0; k < 64; ++k) {
        const float4 qa0 = *(const float4*)&sA[k * SA_STRIDE + ng * 8];
        const float4 qa1 = *(const float4*)&sA[k * SA_STRIDE + ng * 8 + 4];
        const float4 qb  = *(const float4*)&sW[k * SW_STRIDE + cg * 4];
        float av[8] = {qa0.x, qa0.y, qa0.z, qa0.w, qa1.x, qa1.y, qa1.z, qa1.w};
        float bv[4] = {qb.x, qb.y, qb.z, qb.w};
#pragma unroll
        for (int i = 0; i < 8; ++i)
#pragma unroll
            for (int j = 0; j < 4; ++j)
                acc[i][j] = __builtin_fmaf(av[i], bv[j], acc[i][j]);
    }
}

// ---------------------------------------------------------------------------
// Transform (R5-proven structure + two deltas):
//  - pass-B hin tile PREFETCHED into registers before the first barrier, so
//    its global latency overlaps kloop A; after kloop A only reg->LDS scatter.
//  - output head fused into the epilogue on the final layer (out_kernel gone).
// Block tile 128 nodes x 64 ch, thread tile 8x4. io overwritten in place.
// LDS 51 KB -> 3 blocks/CU; launch_bounds(256,3) keeps VGPR under the
// 3-waves/SIMD cap (~170).
// ---------------------------------------------------------------------------
__global__ __launch_bounds__(256, 3) void transform_kernel(
        float* __restrict__ io, const float* __restrict__ hin,
        const float* __restrict__ Wl, const float* __restrict__ bl,
        const float* __restrict__ Wr,
        const float* __restrict__ Wout, const float* __restrict__ bout,
        float* __restrict__ out, int N, int final_flag) {
    __shared__ float sA[64 * SA_STRIDE];
    __shared__ float sW[64 * SW_STRIDE];
    int t = threadIdx.x;
    int node_base = blockIdx.x * 128;
    int ng = t >> 4;   // node group: 8 nodes
    int cg = t & 15;   // channel group: 4 channels

    float acc[8][4];
#pragma unroll
    for (int i = 0; i < 8; ++i)
#pragma unroll
        for (int j = 0; j < 4; ++j) acc[i][j] = 0.f;

    // pass A stage: mean(io) + Wl -> LDS
    stage_tile_T(sA, io, node_base, N, t);
    stage_w_T(sW, Wl, t);

    // prefetch pass-B hin tile into registers (loads in flight across kloop A)
    float4 pf[8];
    {
        int nq = t >> 4, kq = t & 15;
#pragma unroll
        for (int p = 0; p < 8; ++p) {
            int gn = node_base + p * 16 + nq;
            if (gn >= N) gn = N - 1;
            pf[p] = *(const float4*)(hin + (size_t)gn * D + (kq << 2));
        }
    }
    __syncthreads();
    kloop(acc, sA, sW, ng, cg);          // pass A: mean @ Wl^T
    __syncthreads();

    // pass B stage: scatter prefetched hin regs -> sA; Wr -> sW
    {
        int nq = t >> 4, kq = t & 15;
#pragma unroll
        for (int p = 0; p < 8; ++p) {
            int node = p * 16 + nq;
            sA[(kq * 4 + 0) * SA_STRIDE + node] = pf[p].x;
            sA[(kq * 4 + 1) * SA_STRIDE + node] = pf[p].y;
            sA[(kq * 4 + 2) * SA_STRIDE + node] = pf[p].z;
            sA[(kq * 4 + 3) * SA_STRIDE + node] = pf[p].w;
        }
    }
    stage_w_T(sW, Wr, t);
    __syncthreads();
    kloop(acc, sA, sW, ng, cg);          // pass B: hin @ Wr^T

    // epilogue
    const float4 bq = *(const float4*)&bl[cg * 4];
    const float bb[4] = {bq.x, bq.y, bq.z, bq.w};
    if (!final_flag) {
#pragma unroll
        for (int i = 0; i < 8; ++i) {
            int gn = node_base + ng * 8 + i;
            if (gn < N) {
                float4 r;
                float y0 = acc[i][0] + bb[0]; r.x = (y0 >= 0.f) ? y0 : NEG_SLOPE * y0;
                float y1 = acc[i][1] + bb[1]; r.y = (y1 >= 0.f) ? y1 : NEG_SLOPE * y1;
                float y2 = acc[i][2] + bb[2]; r.z = (y2 >= 0.f) ? y2 : NEG_SLOPE * y2;
                float y3 = acc[i][3] + bb[3]; r.w = (y3 >= 0.f) ? y3 : NEG_SLOPE * y3;
                *(float4*)(io + (size_t)gn * D + cg * 4) = r;
            }
        }
    } else {
        // fused head: out[gn] = b_out + sum_ch leaky(y)[ch] * Wout[ch]
        // threads sharing ng are 16 consecutive lanes (t = ng*16 + cg)
        const float4 wq = *(const float4*)&Wout[cg * 4];
        const float wv[4] = {wq.x, wq.y, wq.z, wq.w};
        float bo = bout[0];
#pragma unroll
        for (int i = 0; i < 8; ++i) {
            float p = 0.f;
#pragma unroll
            for (int j = 0; j < 4; ++j) {
                float y = acc[i][j] + bb[j];
                y = (y >= 0.f) ? y : NEG_SLOPE * y;
                p += y * wv[j];
            }
            p += __shfl_xor(p, 1, 64);
            p += __shfl_xor(p, 2, 64);
            p += __shfl_xor(p, 4, 64);
            p += __shfl_xor(p, 8, 64);
            if (cg == 0) {
                int gn = node_base + ng * 8 + i;
                if (gn < N) out[gn] = p + bo;
            }
        }
    }
}

extern "C" void kernel_launch(void* const* d_in, const int* in_sizes, int n_in,
                              void* d_out, int out_size, void* d_ws, size_t ws_size,
                              hipStream_t stream) {
    const float* x    = (const float*)d_in[0];
    const void*  ei   = d_in[1];
    const float* Wl1  = (const float*)d_in[2];
    const float* bl1  = (const float*)d_in[3];
    const float* Wr1  = (const float*)d_in[4];
    const float* Wl2  = (const float*)d_in[5];
    const float* bl2  = (const float*)d_in[6];
    const float* Wr2  = (const float*)d_in[7];
    const float* Wl3  = (const float*)d_in[8];
    const float* bl3  = (const float*)d_in[9];
    const float* Wr3  = (const float*)d_in[10];
    const float* Wout = (const float*)d_in[11];
    const float* bout = (const float*)d_in[12];
    float* out = (float*)d_out;

    int       N = in_sizes[0] / D;
    long long E = (long long)in_sizes[1] / 2;
    int ncb = (N + CB_NODES - 1) >> CB_SHIFT;   // <= MAXCB for N <= 131072

    // workspace layout
    char* ws = (char*)d_ws;
    size_t off = 256;
    int* ccount = (int*)(ws + off); off += 512;
    int* cbase  = (int*)(ws + off); off += 1024;
    int* ccur   = (int*)(ws + off); off += 512;
    int* rowptr = (int*)(ws + off); off += (((size_t)(N + 1) * 4 + 255) / 256) * 256;
    int* adj    = (int*)(ws + off); off += (((size_t)E * 4 + 255) / 256) * 256;
    float* bufA = (float*)(ws + off); off += (size_t)N * D * 4;
    float* bufB = (float*)(ws + off);
    unsigned* ebuf = (unsigned*)bufB;  // consumed by finefill before bufB's first write

    // ---- CSR build via two-level counting sort (once; graph layer-invariant) ----
    hipMemsetAsync(ccount, 0, 512, stream);
    chist_kernel<<<256, 256, 0, stream>>>(ei, E, ccount, ncb);
    cscan_kernel<<<1, 128, 0, stream>>>(ccount, cbase, ccur, rowptr, ncb, N, (int)E);
    int sgrid = (int)((E + CHUNK - 1) / CHUNK);
    scatter_kernel<<<sgrid, 256, 0, stream>>>(ei, E, ccur, ebuf, ncb);
    finefill_kernel<<<ncb, 256, 0, stream>>>(ebuf, cbase, rowptr, adj, N);

    int tgrid = (N + 127) / 128;

    // ---- layer 1: x -> bufA ----
    agg_kernel<<<4096, 256, 0, stream>>>(x, rowptr, adj, bufA, N);
    transform_kernel<<<tgrid, 256, 0, stream>>>(bufA, x, Wl1, bl1, Wr1,
                                                Wout, bout, out, N, 0);
    // ---- layer 2: bufA -> bufB ----
    agg_kernel<<<4096, 256, 0, stream>>>(bufA, rowptr, adj, bufB, N);
    transform_kernel<<<tgrid, 256, 0, stream>>>(bufB, bufA, Wl2, bl2, Wr2,
                                                Wout, bout, out, N, 0);
    // ---- layer 3 + fused head: bufB -> out ----
    agg_kernel<<<4096, 256, 0, stream>>>(bufB, rowptr, adj, bufA, N);
    transform_kernel<<<tgrid, 256, 0, stream>>>(bufA, bufB, Wl3, bl3, Wr3,
                                                Wout, bout, out, N, 1);
}